// Round 6
// baseline (639.620 us; speedup 1.0000x reference)
//
#include <hip/hip_runtime.h>
#include <hip/hip_bf16.h>

#define BB 4
#define SS 1024
#define DD 1024
#define HH 16
#define DKK 64

typedef __bf16 bf16;
typedef __bf16 bf16x8 __attribute__((ext_vector_type(8)));
typedef float f32x4 __attribute__((ext_vector_type(4)));

#define MFMA(a, b, c) __builtin_amdgcn_mfma_f32_16x16x32_bf16((a), (b), (c), 0, 0, 0)

__device__ __forceinline__ bf16x8 load8(const bf16* p) {
    return *reinterpret_cast<const bf16x8*>(p);
}

// load 8 contiguous f32, convert to bf16x8 in registers (16B-aligned src)
__device__ __forceinline__ bf16x8 load8f(const float* p) {
    f32x4 a = *reinterpret_cast<const f32x4*>(p);
    f32x4 b = *reinterpret_cast<const f32x4*>(p + 4);
    bf16x8 o;
    o[0] = (bf16)a[0]; o[1] = (bf16)a[1]; o[2] = (bf16)a[2]; o[3] = (bf16)a[3];
    o[4] = (bf16)b[0]; o[5] = (bf16)b[1]; o[6] = (bf16)b[2]; o[7] = (bf16)b[3];
    return o;
}

// ---------------------------------------------------------------------------
// Kernel 1: QKV projection.  C = x (M=B*S, K=D) @ W^T (N=H*DK, K=D).
// Reads f32 inputs, converts to bf16 fragments in registers.
// Q,K stored [b,h,s,dk] bf16; V stored transposed [b,h,dk,s] bf16.
// ---------------------------------------------------------------------------
__global__ __launch_bounds__(256) void qkv_proj(const float* __restrict__ x,
                                                const float* __restrict__ Wq,
                                                const float* __restrict__ Wk,
                                                const float* __restrict__ Wv,
                                                bf16* __restrict__ Qo,
                                                bf16* __restrict__ Ko,
                                                bf16* __restrict__ Vto) {
    const int lane = threadIdx.x & 63;
    const int wave = threadIdx.x >> 6;
    const int m0 = blockIdx.x * 64 + (wave >> 1) * 32;
    const int n0 = blockIdx.y * 64 + (wave & 1) * 32;
    const int z = blockIdx.z;
    const float* W = (z == 0) ? Wq : ((z == 1) ? Wk : Wv);
    const int lr = lane & 15;
    const int lk8 = (lane >> 4) * 8;

    f32x4 acc[2][2] = {};
    const float* arow0 = x + (size_t)(m0 + lr) * DD + lk8;
    const float* arow1 = arow0 + (size_t)16 * DD;
    const float* brow0 = W + (size_t)(n0 + lr) * DD + lk8;
    const float* brow1 = brow0 + (size_t)16 * DD;

    for (int k0 = 0; k0 < DD; k0 += 32) {
        bf16x8 a0 = load8f(arow0 + k0);
        bf16x8 a1 = load8f(arow1 + k0);
        bf16x8 b0 = load8f(brow0 + k0);
        bf16x8 b1 = load8f(brow1 + k0);
        acc[0][0] = MFMA(a0, b0, acc[0][0]);
        acc[0][1] = MFMA(a0, b1, acc[0][1]);
        acc[1][0] = MFMA(a1, b0, acc[1][0]);
        acc[1][1] = MFMA(a1, b1, acc[1][1]);
    }

    for (int i = 0; i < 2; i++)
        for (int j = 0; j < 2; j++)
            for (int r = 0; r < 4; r++) {
                int m = m0 + i * 16 + (lane >> 4) * 4 + r;  // global row (b*S+s)
                int n = n0 + j * 16 + lr;                   // global col (h*DK+dk)
                int b = m >> 10, s = m & 1023;
                int h = n >> 6, dk = n & 63;
                bf16 v = (bf16)acc[i][j][r];
                if (z == 2) {
                    Vto[(((size_t)(b * HH + h)) * DKK + dk) * SS + s] = v;
                } else {
                    bf16* dst = (z == 0) ? Qo : Ko;
                    dst[(((size_t)(b * HH + h)) * SS + s) * DKK + dk] = v;
                }
            }
}

// ---------------------------------------------------------------------------
// Kernel 2: attention per (b,h).  Block = 4 waves; wave w owns 16 q-rows.
// Sweep 1: online row max+sum over causal k-tiles.
// Sweep 2: recompute scores, write normalized f32 weights (zeros above the
// diagonal), stage bf16 P via LDS, accumulate O = P @ V with MFMA.
// ---------------------------------------------------------------------------
__global__ __launch_bounds__(256) void attn(const bf16* __restrict__ Q,
                                            const bf16* __restrict__ K,
                                            const bf16* __restrict__ Vt,
                                            float* __restrict__ Wgt,
                                            bf16* __restrict__ Ctx) {
    const int lane = threadIdx.x & 63;
    const int wave = threadIdx.x >> 6;
    const int bh = blockIdx.y;                  // b*H + h
    const int q0 = blockIdx.x * 64 + wave * 16; // this wave's first q row
    const int lr = lane & 15;
    const int lk8 = (lane >> 4) * 8;
    const int rbase = (lane >> 4) * 4;

    const bf16* Qb = Q + (size_t)bh * SS * DKK;
    const bf16* Kb = K + (size_t)bh * SS * DKK;
    const bf16* Vb = Vt + (size_t)bh * SS * DKK;

    bf16x8 qa0 = load8(Qb + (size_t)(q0 + lr) * DKK + lk8);
    bf16x8 qa1 = load8(Qb + (size_t)(q0 + lr) * DKK + 32 + lk8);

    const int num_kt = q0 / 16 + 1;  // causal: tiles 0 .. q0/16 inclusive

    float mrow[4], srow[4];
    for (int r = 0; r < 4; r++) { mrow[r] = -1e30f; srow[r] = 0.f; }

    // ---- sweep 1: row max + sum(exp) ----
    for (int kt = 0; kt < num_kt; kt++) {
        bf16x8 kb0 = load8(Kb + (size_t)(kt * 16 + lr) * DKK + lk8);
        bf16x8 kb1 = load8(Kb + (size_t)(kt * 16 + lr) * DKK + 32 + lk8);
        f32x4 sc = {};
        sc = MFMA(qa0, kb0, sc);
        sc = MFMA(qa1, kb1, sc);
        int kcol = kt * 16 + lr;
        for (int r = 0; r < 4; r++) {
            int qrow = q0 + rbase + r;
            float s = sc[r] * 0.125f;
            if (kcol > qrow) s = -1e30f;
            float v = s;
            v = fmaxf(v, __shfl_xor(v, 1));
            v = fmaxf(v, __shfl_xor(v, 2));
            v = fmaxf(v, __shfl_xor(v, 4));
            v = fmaxf(v, __shfl_xor(v, 8));
            float newm = fmaxf(mrow[r], v);
            float e = __expf(s - newm);
            float rs = e;
            rs += __shfl_xor(rs, 1);
            rs += __shfl_xor(rs, 2);
            rs += __shfl_xor(rs, 4);
            rs += __shfl_xor(rs, 8);
            srow[r] = srow[r] * __expf(mrow[r] - newm) + rs;
            mrow[r] = newm;
        }
    }
    float inv[4];
    for (int r = 0; r < 4; r++) inv[r] = 1.f / srow[r];

    // ---- sweep 2: f32 weights write + PV accumulate ----
    f32x4 oacc[4] = {};
    __shared__ __align__(16) bf16 lds_p[4][16][40];  // per-wave P tile, 80B row stride

    for (int kt2 = 0; kt2 < SS / 32; kt2++) {
        __syncthreads();  // WAR: previous iteration's LDS reads done
        for (int t = 0; t < 2; t++) {
            int kt = kt2 * 2 + t;
            int kcol = kt * 16 + lr;
            if (kt < num_kt) {
                bf16x8 kb0 = load8(Kb + (size_t)(kt * 16 + lr) * DKK + lk8);
                bf16x8 kb1 = load8(Kb + (size_t)(kt * 16 + lr) * DKK + 32 + lk8);
                f32x4 sc = {};
                sc = MFMA(qa0, kb0, sc);
                sc = MFMA(qa1, kb1, sc);
                for (int r = 0; r < 4; r++) {
                    int rloc = rbase + r;
                    int qrow = q0 + rloc;
                    float s = sc[r] * 0.125f;
                    float p = (kcol <= qrow) ? __expf(s - mrow[r]) * inv[r] : 0.f;
                    Wgt[((size_t)bh * SS + qrow) * SS + kcol] = p;
                    lds_p[wave][rloc][t * 16 + lr] = (bf16)p;
                }
            } else {
                for (int r = 0; r < 4; r++) {
                    int rloc = rbase + r;
                    int qrow = q0 + rloc;
                    Wgt[((size_t)bh * SS + qrow) * SS + kcol] = 0.f;
                    lds_p[wave][rloc][t * 16 + lr] = (bf16)0.f;
                }
            }
        }
        __syncthreads();  // RAW: P tile visible
        if (kt2 * 2 < num_kt) {
            bf16x8 pf = *reinterpret_cast<const bf16x8*>(&lds_p[wave][lr][lk8]);
            for (int j = 0; j < 4; j++) {
                bf16x8 vb = load8(Vb + (size_t)(j * 16 + lr) * SS + kt2 * 32 + lk8);
                oacc[j] = MFMA(pf, vb, oacc[j]);
            }
        }
    }

    const int b = bh >> 4, h = bh & 15;
    for (int j = 0; j < 4; j++)
        for (int r = 0; r < 4; r++) {
            int qrow = q0 + rbase + r;
            int col = h * 64 + j * 16 + lr;
            Ctx[((size_t)b * SS + qrow) * DD + col] = (bf16)oacc[j][r];
        }
}

// ---------------------------------------------------------------------------
// Kernel 3: output projection.  out = ctx (M=B*S, K=D) @ Wo^T (N=D, K=D).
// Ctx is bf16 workspace; Wo is f32 converted in registers; output stored f32.
// ---------------------------------------------------------------------------
__global__ __launch_bounds__(256) void out_proj(const bf16* __restrict__ Ctx,
                                                const float* __restrict__ Wo,
                                                float* __restrict__ Out) {
    const int lane = threadIdx.x & 63;
    const int wave = threadIdx.x >> 6;
    const int m0 = blockIdx.x * 64 + (wave >> 1) * 32;
    const int n0 = blockIdx.y * 64 + (wave & 1) * 32;
    const int lr = lane & 15;
    const int lk8 = (lane >> 4) * 8;

    f32x4 acc[2][2] = {};
    const bf16* arow0 = Ctx + (size_t)(m0 + lr) * DD + lk8;
    const bf16* arow1 = arow0 + (size_t)16 * DD;
    const float* brow0 = Wo + (size_t)(n0 + lr) * DD + lk8;
    const float* brow1 = brow0 + (size_t)16 * DD;

    for (int k0 = 0; k0 < DD; k0 += 32) {
        bf16x8 a0 = load8(arow0 + k0);
        bf16x8 a1 = load8(arow1 + k0);
        bf16x8 b0 = load8f(brow0 + k0);
        bf16x8 b1 = load8f(brow1 + k0);
        acc[0][0] = MFMA(a0, b0, acc[0][0]);
        acc[0][1] = MFMA(a0, b1, acc[0][1]);
        acc[1][0] = MFMA(a1, b0, acc[1][0]);
        acc[1][1] = MFMA(a1, b1, acc[1][1]);
    }

    for (int i = 0; i < 2; i++)
        for (int j = 0; j < 2; j++)
            for (int r = 0; r < 4; r++) {
                int m = m0 + i * 16 + (lane >> 4) * 4 + r;
                int n = n0 + j * 16 + lr;
                Out[(size_t)m * DD + n] = acc[i][j][r];
            }
}

// ---------------------------------------------------------------------------
extern "C" void kernel_launch(void* const* d_in, const int* in_sizes, int n_in,
                              void* d_out, int out_size, void* d_ws, size_t ws_size,
                              hipStream_t stream) {
    const float* x  = (const float*)d_in[0];
    const float* Wq = (const float*)d_in[1];
    const float* Wk = (const float*)d_in[2];
    const float* Wv = (const float*)d_in[3];
    const float* Wo = (const float*)d_in[4];
    // d_in[5] is the causal mask — static, handled analytically.

    float* out = (float*)d_out;                     // output (B,S,D) f32, 4M elems
    float* wgt = out + (size_t)BB * SS * DD;        // weights (B,H,S,S) f32, 64M

    // bf16 workspace — 32 MB total
    bf16* qws = (bf16*)d_ws;                        // Q  [b,h,s,dk]   8 MB
    bf16* kws = qws + (size_t)BB * HH * SS * DKK;   // K  [b,h,s,dk]   8 MB
    bf16* vws = kws + (size_t)BB * HH * SS * DKK;   // Vt [b,h,dk,s]   8 MB
    bf16* cws = vws + (size_t)BB * HH * SS * DKK;   // concat [b,s,d]  8 MB

    qkv_proj<<<dim3(64, 16, 3), 256, 0, stream>>>(x, Wq, Wk, Wv, qws, kws, vws);
    attn<<<dim3(16, 64), 256, 0, stream>>>(qws, kws, vws, wgt, cws);
    out_proj<<<dim3(64, 16), 256, 0, stream>>>(cws, Wo, out);
}

// Round 7
// 290.904 us; speedup vs baseline: 2.1987x; 2.1987x over previous
//
#include <hip/hip_runtime.h>
#include <hip/hip_bf16.h>

#define BB 4
#define SS 1024
#define DD 1024
#define HH 16
#define DKK 64

typedef __bf16 bf16;
typedef __bf16 bf16x8 __attribute__((ext_vector_type(8)));
typedef __bf16 bf16x4 __attribute__((ext_vector_type(4)));
typedef float f32x4 __attribute__((ext_vector_type(4)));

#define MFMA(a, b, c) __builtin_amdgcn_mfma_f32_16x16x32_bf16((a), (b), (c), 0, 0, 0)

__device__ __forceinline__ bf16x8 load8(const bf16* p) {
    return *reinterpret_cast<const bf16x8*>(p);
}

// ---------------------------------------------------------------------------
// Kernel 0: f32 -> bf16 conversion.  dst layout (elements):
//   [0,4M): x   [4M,7M): Wq|Wk|Wv concat   [7M,8M): Wo
// ---------------------------------------------------------------------------
__global__ __launch_bounds__(256) void cvt_bf16(const float* __restrict__ x,
                                                const float* __restrict__ Wq,
                                                const float* __restrict__ Wk,
                                                const float* __restrict__ Wv,
                                                const float* __restrict__ Wo,
                                                bf16* __restrict__ dst) {
    const size_t MEG = 1024 * 1024;
    size_t e = ((size_t)blockIdx.x * 256 + threadIdx.x) * 4;
    const float* src;
    size_t off;
    if (e < 4 * MEG)      { src = x;  off = e; }
    else if (e < 5 * MEG) { src = Wq; off = e - 4 * MEG; }
    else if (e < 6 * MEG) { src = Wk; off = e - 5 * MEG; }
    else if (e < 7 * MEG) { src = Wv; off = e - 6 * MEG; }
    else                  { src = Wo; off = e - 7 * MEG; }
    f32x4 v = *reinterpret_cast<const f32x4*>(src + off);
    bf16x4 o;
    o[0] = (bf16)v[0]; o[1] = (bf16)v[1]; o[2] = (bf16)v[2]; o[3] = (bf16)v[3];
    *reinterpret_cast<bf16x4*>(dst + e) = o;
}

// ---------------------------------------------------------------------------
// 128x128-tile LDS-staged bf16 GEMM:  C = A (Mx1024) @ B^T (Nx1024).
// BK=32, 4 waves (2x2), each wave 64x64 out.  XOR-swizzled LDS chunks
// (chunk ^= row&3) -> ds_read/ds_write conflicts reduced to free 2-way.
// Register prefetch of next K-step hides global latency under MFMA.
// MODE 0: N=3072 (Wq|Wk|Wv), writes Q,K [b,h,s,dk] + Vt [b,h,dk,s] bf16.
// MODE 1: N=1024, writes f32 Out row-major.
// ---------------------------------------------------------------------------
template <int MODE>
__global__ __launch_bounds__(256) void gemm128(const bf16* __restrict__ A,
                                               const bf16* __restrict__ Bm,
                                               void* __restrict__ o0,
                                               void* __restrict__ o1,
                                               void* __restrict__ o2) {
    const int lane = threadIdx.x & 63;
    const int wave = threadIdx.x >> 6;
    const int wr = wave >> 1, wc = wave & 1;
    const int m0 = blockIdx.x * 128;
    const int n0 = blockIdx.y * 128;
    const int K = DD;

    __shared__ __align__(16) bf16 As[128][32];
    __shared__ __align__(16) bf16 Bs[128][32];

    // staging map: thread t covers rows (t>>2, t>>2+64), 16B chunk t&3
    const int srow = threadIdx.x >> 2;
    const int schk = threadIdx.x & 3;
    const int swz = (schk ^ (srow & 3)) * 8;  // (srow+64)&3 == srow&3

    const bf16* Ag0 = A + (size_t)(m0 + srow) * K + schk * 8;
    const bf16* Ag1 = Ag0 + (size_t)64 * K;
    const bf16* Bg0 = Bm + (size_t)(n0 + srow) * K + schk * 8;
    const bf16* Bg1 = Bg0 + (size_t)64 * K;

    bf16* Aw0 = &As[srow][swz];
    bf16* Aw1 = &As[srow + 64][swz];
    bf16* Bw0 = &Bs[srow][swz];
    bf16* Bw1 = &Bs[srow + 64][swz];

    // fragment read: row = w*64 + i*16 + (lane&15); data-chunk (lane>>4) was
    // stored at position (lane>>4) ^ (row&3) = (lane>>4) ^ (lane&3)
    const int rsw = ((lane >> 4) ^ (lane & 3)) * 8;
    const int rrow = lane & 15;

    f32x4 acc[4][4] = {};

    bf16x8 ra0 = load8(Ag0), ra1 = load8(Ag1);
    bf16x8 rb0 = load8(Bg0), rb1 = load8(Bg1);

    for (int k0 = 0; k0 < K; k0 += 32) {
        __syncthreads();  // WAR: previous iteration's ds_reads complete
        *reinterpret_cast<bf16x8*>(Aw0) = ra0;
        *reinterpret_cast<bf16x8*>(Aw1) = ra1;
        *reinterpret_cast<bf16x8*>(Bw0) = rb0;
        *reinterpret_cast<bf16x8*>(Bw1) = rb1;
        __syncthreads();
        if (k0 + 32 < K) {  // prefetch next K-step into regs (T14-style)
            ra0 = load8(Ag0 + k0 + 32);
            ra1 = load8(Ag1 + k0 + 32);
            rb0 = load8(Bg0 + k0 + 32);
            rb1 = load8(Bg1 + k0 + 32);
        }
        bf16x8 af[4], bfr[4];
#pragma unroll
        for (int i = 0; i < 4; i++)
            af[i] = *reinterpret_cast<const bf16x8*>(&As[wr * 64 + i * 16 + rrow][rsw]);
#pragma unroll
        for (int j = 0; j < 4; j++)
            bfr[j] = *reinterpret_cast<const bf16x8*>(&Bs[wc * 64 + j * 16 + rrow][rsw]);
#pragma unroll
        for (int i = 0; i < 4; i++)
#pragma unroll
            for (int j = 0; j < 4; j++)
                acc[i][j] = MFMA(af[i], bfr[j], acc[i][j]);
    }

    if constexpr (MODE == 0) {
        bf16* Qo = (bf16*)o0;
        bf16* Ko = (bf16*)o1;
        bf16* Vto = (bf16*)o2;
        const int z = n0 >> 10;  // uniform per block (128 | 1024)
#pragma unroll
        for (int i = 0; i < 4; i++)
#pragma unroll
            for (int j = 0; j < 4; j++)
#pragma unroll
                for (int r = 0; r < 4; r++) {
                    int m = m0 + wr * 64 + i * 16 + (lane >> 4) * 4 + r;
                    int n = n0 + wc * 64 + j * 16 + (lane & 15);
                    int b = m >> 10, s = m & 1023;
                    int nn = n & 1023, h = nn >> 6, dk = nn & 63;
                    bf16 v = (bf16)acc[i][j][r];
                    if (z == 0)
                        Qo[(((size_t)(b * HH + h)) * SS + s) * DKK + dk] = v;
                    else if (z == 1)
                        Ko[(((size_t)(b * HH + h)) * SS + s) * DKK + dk] = v;
                    else
                        Vto[(((size_t)(b * HH + h)) * DKK + dk) * SS + s] = v;
                }
    } else {
        float* Out = (float*)o0;
#pragma unroll
        for (int i = 0; i < 4; i++)
#pragma unroll
            for (int j = 0; j < 4; j++)
#pragma unroll
                for (int r = 0; r < 4; r++) {
                    int m = m0 + wr * 64 + i * 16 + (lane >> 4) * 4 + r;
                    int n = n0 + wc * 64 + j * 16 + (lane & 15);
                    Out[(size_t)m * DD + n] = acc[i][j][r];
                }
    }
}

// ---------------------------------------------------------------------------
// Kernel 2: attention per (b,h) — unchanged from the passing round.
// ---------------------------------------------------------------------------
__global__ __launch_bounds__(256) void attn(const bf16* __restrict__ Q,
                                            const bf16* __restrict__ K,
                                            const bf16* __restrict__ Vt,
                                            float* __restrict__ Wgt,
                                            bf16* __restrict__ Ctx) {
    const int lane = threadIdx.x & 63;
    const int wave = threadIdx.x >> 6;
    const int bh = blockIdx.y;                  // b*H + h
    const int q0 = blockIdx.x * 64 + wave * 16; // this wave's first q row
    const int lr = lane & 15;
    const int lk8 = (lane >> 4) * 8;
    const int rbase = (lane >> 4) * 4;

    const bf16* Qb = Q + (size_t)bh * SS * DKK;
    const bf16* Kb = K + (size_t)bh * SS * DKK;
    const bf16* Vb = Vt + (size_t)bh * SS * DKK;

    bf16x8 qa0 = load8(Qb + (size_t)(q0 + lr) * DKK + lk8);
    bf16x8 qa1 = load8(Qb + (size_t)(q0 + lr) * DKK + 32 + lk8);

    const int num_kt = q0 / 16 + 1;  // causal: tiles 0 .. q0/16 inclusive

    float mrow[4], srow[4];
    for (int r = 0; r < 4; r++) { mrow[r] = -1e30f; srow[r] = 0.f; }

    // ---- sweep 1: row max + sum(exp) ----
    for (int kt = 0; kt < num_kt; kt++) {
        bf16x8 kb0 = load8(Kb + (size_t)(kt * 16 + lr) * DKK + lk8);
        bf16x8 kb1 = load8(Kb + (size_t)(kt * 16 + lr) * DKK + 32 + lk8);
        f32x4 sc = {};
        sc = MFMA(qa0, kb0, sc);
        sc = MFMA(qa1, kb1, sc);
        int kcol = kt * 16 + lr;
        for (int r = 0; r < 4; r++) {
            int qrow = q0 + rbase + r;
            float s = sc[r] * 0.125f;
            if (kcol > qrow) s = -1e30f;
            float v = s;
            v = fmaxf(v, __shfl_xor(v, 1));
            v = fmaxf(v, __shfl_xor(v, 2));
            v = fmaxf(v, __shfl_xor(v, 4));
            v = fmaxf(v, __shfl_xor(v, 8));
            float newm = fmaxf(mrow[r], v);
            float e = __expf(s - newm);
            float rs = e;
            rs += __shfl_xor(rs, 1);
            rs += __shfl_xor(rs, 2);
            rs += __shfl_xor(rs, 4);
            rs += __shfl_xor(rs, 8);
            srow[r] = srow[r] * __expf(mrow[r] - newm) + rs;
            mrow[r] = newm;
        }
    }
    float inv[4];
    for (int r = 0; r < 4; r++) inv[r] = 1.f / srow[r];

    // ---- sweep 2: f32 weights write + PV accumulate ----
    f32x4 oacc[4] = {};
    __shared__ __align__(16) bf16 lds_p[4][16][40];

    for (int kt2 = 0; kt2 < SS / 32; kt2++) {
        __syncthreads();
        for (int t = 0; t < 2; t++) {
            int kt = kt2 * 2 + t;
            int kcol = kt * 16 + lr;
            if (kt < num_kt) {
                bf16x8 kb0 = load8(Kb + (size_t)(kt * 16 + lr) * DKK + lk8);
                bf16x8 kb1 = load8(Kb + (size_t)(kt * 16 + lr) * DKK + 32 + lk8);
                f32x4 sc = {};
                sc = MFMA(qa0, kb0, sc);
                sc = MFMA(qa1, kb1, sc);
                for (int r = 0; r < 4; r++) {
                    int rloc = rbase + r;
                    int qrow = q0 + rloc;
                    float s = sc[r] * 0.125f;
                    float p = (kcol <= qrow) ? __expf(s - mrow[r]) * inv[r] : 0.f;
                    Wgt[((size_t)bh * SS + qrow) * SS + kcol] = p;
                    lds_p[wave][rloc][t * 16 + lr] = (bf16)p;
                }
            } else {
                for (int r = 0; r < 4; r++) {
                    int rloc = rbase + r;
                    int qrow = q0 + rloc;
                    Wgt[((size_t)bh * SS + qrow) * SS + kcol] = 0.f;
                    lds_p[wave][rloc][t * 16 + lr] = (bf16)0.f;
                }
            }
        }
        __syncthreads();
        if (kt2 * 2 < num_kt) {
            bf16x8 pf = *reinterpret_cast<const bf16x8*>(&lds_p[wave][lr][lk8]);
            for (int j = 0; j < 4; j++) {
                bf16x8 vb = load8(Vb + (size_t)(j * 16 + lr) * SS + kt2 * 32 + lk8);
                oacc[j] = MFMA(pf, vb, oacc[j]);
            }
        }
    }

    const int b = bh >> 4, h = bh & 15;
    for (int j = 0; j < 4; j++)
        for (int r = 0; r < 4; r++) {
            int qrow = q0 + rbase + r;
            int col = h * 64 + j * 16 + lr;
            Ctx[((size_t)b * SS + qrow) * DD + col] = (bf16)oacc[j][r];
        }
}

// ---------------------------------------------------------------------------
extern "C" void kernel_launch(void* const* d_in, const int* in_sizes, int n_in,
                              void* d_out, int out_size, void* d_ws, size_t ws_size,
                              hipStream_t stream) {
    const float* x  = (const float*)d_in[0];
    const float* Wq = (const float*)d_in[1];
    const float* Wk = (const float*)d_in[2];
    const float* Wv = (const float*)d_in[3];
    const float* Wo = (const float*)d_in[4];
    // d_in[5] is the causal mask — static, handled analytically.

    float* out = (float*)d_out;                     // output (B,S,D) f32
    float* wgt = out + (size_t)BB * SS * DD;        // weights (B,H,S,S) f32

    const size_t MEG = 1024 * 1024;
    bf16* xb   = (bf16*)d_ws;         // x bf16        [0,4M)
    bf16* wcat = xb + 4 * MEG;        // Wq|Wk|Wv bf16 [4M,7M)
    bf16* wob  = xb + 7 * MEG;        // Wo bf16       [7M,8M)
    bf16* qws  = xb + 8 * MEG;        // Q  [b,h,s,dk]
    bf16* kws  = xb + 12 * MEG;       // K  [b,h,s,dk]
    bf16* vws  = xb + 16 * MEG;       // Vt [b,h,dk,s]
    bf16* cws  = xb + 20 * MEG;       // concat ctx [b,s,d]

    cvt_bf16<<<dim3(8192), 256, 0, stream>>>(x, Wq, Wk, Wv, Wo, xb);
    gemm128<0><<<dim3(32, 24), 256, 0, stream>>>(xb, wcat, qws, kws, vws);
    attn<<<dim3(16, 64), 256, 0, stream>>>(qws, kws, vws, wgt, cws);
    gemm128<1><<<dim3(32, 8), 256, 0, stream>>>(cws, wob, out, nullptr, nullptr);
}